// Round 7
// baseline (3821.889 us; speedup 1.0000x reference)
//
#include <hip/hip_runtime.h>
#include <cstdint>

#define Hn 36
#define G4 144          // 4*H gate rows
#define TT 512
#define BB 2048

__device__ __forceinline__ float sigf(float x) { return 1.0f / (1.0f + __expf(-x)); }
__device__ __forceinline__ float tanh_fast(float x) {
    float e = __expf(2.0f * x);          // exact +-1 limits via over/underflow
    return 1.0f - 2.0f / (e + 1.0f);
}

// ---- named-register weight quads (no arrays -> no allocas -> no scratch) ----
#define DECLQ(P, i) float P##i##x, P##i##y, P##i##z, P##i##w;
#define LOADQ(P, i) { float4 _t = wp[i]; P##i##x = _t.x; P##i##y = _t.y; P##i##z = _t.z; P##i##w = _t.w; }
#define ZEROQ(P, i) { P##i##x = 0.f; P##i##y = 0.f; P##i##z = 0.f; P##i##w = 0.f; }
#define PINQ(P, i)  asm volatile("" : "+v"(P##i##x), "+v"(P##i##y), "+v"(P##i##z), "+v"(P##i##w));
#define FMAQ(P, i)                                                        \
    {  float4 hv = *(const float4*)&hb[(i) * 4];                          \
       z0 = fmaf(P##i##x, hv.x, z0); z1 = fmaf(P##i##y, hv.y, z1);        \
       z2 = fmaf(P##i##z, hv.z, z2); z3 = fmaf(P##i##w, hv.w, z3); }

#define REP5(M, P) M(P,0) M(P,1) M(P,2) M(P,3) M(P,4)
#define REP9Q(M, P) REP5(M, P) M(P,5) M(P,6) M(P,7) M(P,8)

// array-based dots (fallback kernel only — unused when workspace is present)
#define DOT36(W, H, Z0, Z1, Z2, Z3)                        \
    do {                                                   \
        _Pragma("unroll") for (int _k = 0; _k < 9; ++_k) { \
            float4 hv = *(const float4*)&(H)[_k * 4];      \
            Z0 = fmaf((W)[_k * 4 + 0], hv.x, Z0);          \
            Z1 = fmaf((W)[_k * 4 + 1], hv.y, Z1);          \
            Z2 = fmaf((W)[_k * 4 + 2], hv.z, Z2);          \
            Z3 = fmaf((W)[_k * 4 + 3], hv.w, Z3);          \
        }                                                  \
    } while (0)

#define DOT72(W, H, Z0, Z1, Z2, Z3)                         \
    do {                                                    \
        _Pragma("unroll") for (int _k = 0; _k < 18; ++_k) { \
            float4 hv = *(const float4*)&(H)[_k * 4];       \
            Z0 = fmaf((W)[_k * 4 + 0], hv.x, Z0);           \
            Z1 = fmaf((W)[_k * 4 + 1], hv.y, Z1);           \
            Z2 = fmaf((W)[_k * 4 + 2], hv.z, Z2);           \
            Z3 = fmaf((W)[_k * 4 + 3], hv.w, Z3);           \
        }                                                   \
    } while (0)

// ======================= PRIMARY PATH (needs 151 MB ws) ======================
// Kernel 1: layer-0 reverse scan -> h0r (B, T, 36) fp32 in workspace.
// One thread per gate row (36 weights/thread — well under budget, no split).
#define CH0 4
#define NT0 (CH0 * G4)   // 576
__global__ __launch_bounds__(NT0)
__attribute__((amdgpu_waves_per_eu(1, 4)))
void l0rev_kernel(
    const float* __restrict__ x,
    const float* __restrict__ Wih, const float* __restrict__ Whh,
    const float* __restrict__ bih, const float* __restrict__ bhh,
    float* __restrict__ h0r)
{
    const int tid = threadIdx.x;
    const int cc  = tid / G4;
    const int g   = tid % G4;
    const int b   = blockIdx.x * CH0 + cc;

    __shared__ float xs[CH0][TT];
    __shared__ float hs[CH0][40];
    __shared__ float zs[CH0][G4];

    for (int i = g; i < TT; i += G4) xs[cc][i] = x[(size_t)b * TT + i];

    REP9Q(DECLQ, R)
    {
        const float4* wp = (const float4*)(Whh + g * Hn);   // 144B rows, 16B-aligned
        REP9Q(LOADQ, R)
    }
    float wx   = Wih[g];
    float bias = bih[g] + bhh[g];
    REP9Q(PINQ, R)
    asm volatile("" : "+v"(wx), "+v"(bias));

    if (g < 40) hs[cc][g] = 0.0f;
    float c = 0.0f;
    __syncthreads();

    float* rrow = h0r + (size_t)b * TT * Hn;
    for (int s = 0; s < TT; ++s) {
        const int t = TT - 1 - s;
        float z0 = fmaf(xs[cc][t], wx, bias), z1 = 0.f, z2 = 0.f, z3 = 0.f;
        {
            const float* hb = hs[cc];
            REP9Q(FMAQ, R)
        }
        zs[cc][g] = (z0 + z1) + (z2 + z3);
        __syncthreads();
        if (g < Hn) {
            float zi = zs[cc][g], zf = zs[cc][g + 36], zg = zs[cc][g + 72], zo = zs[cc][g + 108];
            c = sigf(zf) * c + sigf(zi) * tanh_fast(zg);
            float h = sigf(zo) * tanh_fast(c);
            hs[cc][g] = h;
            rrow[(size_t)t * Hn + g] = h;
        }
        __syncthreads();
    }
}

// Kernel 2: fused L0-fwd + L1-fwd + single-step L1-rev + FC.
// 2-way row split: thread (cc, half, g) computes half the K-range of row g.
// Per-thread weights: A 5 quads + I 9 quads + H 5 quads = 76 floats (half1
// zero-pads the 5th A/H quad; the LDS pads it reads are initialized to 0).
#define NT1 576          // 2 chains x 2 halves x 144 rows = 9 waves
__global__ __launch_bounds__(NT1)
__attribute__((amdgpu_waves_per_eu(1, 4)))
void fused_fwd_kernel(
    const float* __restrict__ x,
    const float* __restrict__ Wih0f, const float* __restrict__ Whh0f,
    const float* __restrict__ bih0f, const float* __restrict__ bhh0f,
    const float* __restrict__ Wih1f, const float* __restrict__ Whh1f,
    const float* __restrict__ bih1f, const float* __restrict__ bhh1f,
    const float* __restrict__ Wih1r,
    const float* __restrict__ bih1r, const float* __restrict__ bhh1r,
    const float* __restrict__ fcW, const float* __restrict__ fcb,
    const float* __restrict__ h0r,
    float* __restrict__ out)
{
    const int tid  = threadIdx.x;
    const int cc   = tid / 288;     // chain in block
    const int r    = tid % 288;
    const int half = r / G4;        // K-range half
    const int g    = r % G4;        // gate row
    const int b    = blockIdx.x * 2 + cc;

    __shared__ float xs[2][TT];
    __shared__ float h0s[2][80];      // [h0f(36) | h0r(36) | pad(8)]
    __shared__ float hs1[2][40];      // [h1(36) | pad(4)]
    __shared__ float zsP[2][2][G4];   // per-half partial sums
    __shared__ float red[2][40];

    for (int i = r; i < TT; i += 288) xs[cc][i] = x[(size_t)b * TT + i];

    REP5(DECLQ, A) REP9Q(DECLQ, I) REP5(DECLQ, H)
    {
        const float4* wp = (const float4*)(Whh0f + g * Hn + half * 20);
        LOADQ(A, 0) LOADQ(A, 1) LOADQ(A, 2) LOADQ(A, 3)
        if (!half) { LOADQ(A, 4) } else { ZEROQ(A, 4) }
    }
    {
        const float4* wp = (const float4*)(Wih1f + g * 72 + half * 36);
        REP9Q(LOADQ, I)
    }
    {
        const float4* wp = (const float4*)(Whh1f + g * Hn + half * 20);
        LOADQ(H, 0) LOADQ(H, 1) LOADQ(H, 2) LOADQ(H, 3)
        if (!half) { LOADQ(H, 4) } else { ZEROQ(H, 4) }
    }
    float wx0 = 0.f, b0 = 0.f, b1 = 0.f;
    if (!half) {
        wx0 = Wih0f[g];
        b0  = bih0f[g] + bhh0f[g];
        b1  = bih1f[g] + bhh1f[g];
    }
    REP5(PINQ, A) REP9Q(PINQ, I) REP5(PINQ, H)
    asm volatile("" : "+v"(wx0), "+v"(b0), "+v"(b1));

    if (r < 40) { h0s[cc][r] = 0.0f; h0s[cc][40 + r] = 0.0f; hs1[cc][r] = 0.0f; }
    float c0 = 0.0f, c1 = 0.0f;

    const float* rrow = h0r + (size_t)b * TT * Hn;
    float rv = (half == 1 && g < Hn) ? rrow[g] : 0.0f;   // h0r(t=0)
    __syncthreads();

    for (int t = 0; t < TT; ++t) {
        // ---- phase A: layer-0 forward (dot over this half's K-range) ----
        float z0 = half ? 0.f : fmaf(xs[cc][t], wx0, b0);
        float z1 = 0.f, z2 = 0.f, z3 = 0.f;
        {
            const float* hb = &h0s[cc][half * 20];
            REP5(FMAQ, A)
        }
        zsP[cc][half][g] = (z0 + z1) + (z2 + z3);
        __syncthreads();
        if (r < Hn) {                       // half0, g<36: gate combine
            float zi = zsP[cc][0][g]       + zsP[cc][1][g];
            float zf = zsP[cc][0][g + 36]  + zsP[cc][1][g + 36];
            float zg = zsP[cc][0][g + 72]  + zsP[cc][1][g + 72];
            float zo = zsP[cc][0][g + 108] + zsP[cc][1][g + 108];
            c0 = sigf(zf) * c0 + sigf(zi) * tanh_fast(zg);
            h0s[cc][g] = sigf(zo) * tanh_fast(c0);
        } else if (half == 1 && g < Hn) {   // insert h0r(t)
            h0s[cc][36 + g] = rv;
        }
        __syncthreads();
        if (half == 1 && g < Hn && t + 1 < TT)   // prefetch h0r(t+1)
            rv = rrow[(size_t)(t + 1) * Hn + g];

        // ---- phase B: layer-1 forward ----
        z0 = half ? 0.f : b1; z1 = 0.f; z2 = 0.f; z3 = 0.f;
        {
            const float* hb = &h0s[cc][half * 36];   // 36 floats of h0cat
            REP9Q(FMAQ, I)
        }
        {
            const float* hb = &hs1[cc][half * 20];
            REP5(FMAQ, H)
        }
        zsP[cc][half][g] = (z0 + z1) + (z2 + z3);
        __syncthreads();
        if (r < Hn) {
            float zi = zsP[cc][0][g]       + zsP[cc][1][g];
            float zf = zsP[cc][0][g + 36]  + zsP[cc][1][g + 36];
            float zg = zsP[cc][0][g + 72]  + zsP[cc][1][g + 72];
            float zo = zsP[cc][0][g + 108] + zsP[cc][1][g + 108];
            c1 = sigf(zf) * c1 + sigf(zi) * tanh_fast(zg);
            hs1[cc][g] = sigf(zo) * tanh_fast(c1);
        }
        __syncthreads();
    }

    // ---- tail: L1 reverse single step at t=T-1 (h0=c0=0) + FC ----
    {
        float z = 0.f;
        const float* wr = Wih1r + g * 72 + half * 36;
        const float* hb = &h0s[cc][half * 36];
#pragma unroll
        for (int k = 0; k < 36; ++k) z = fmaf(wr[k], hb[k], z);
        if (!half) z += bih1r[g] + bhh1r[g];
        zsP[cc][half][g] = z;
    }
    __syncthreads();
    if (r < Hn) {
        float zi = zsP[cc][0][g]       + zsP[cc][1][g];
        float zg = zsP[cc][0][g + 72]  + zsP[cc][1][g + 72];
        float zo = zsP[cc][0][g + 108] + zsP[cc][1][g + 108];
        float c  = sigf(zi) * tanh_fast(zg);     // c0=0: forget term vanishes
        float hr = sigf(zo) * tanh_fast(c);
        red[cc][g] = fcW[36 + g] * hr + fcW[g] * hs1[cc][g];
    }
    __syncthreads();
    if (r == 0) {
        float s = fcb[0];
        for (int j = 0; j < Hn; ++j) s += red[cc][j];
        out[b] = s;
    }
}

// ================= FALLBACK PATH (zero workspace, ckpt/recompute) ============
// Unused when the harness provides >=151MB workspace (it does today).
__global__ __launch_bounds__(G4, 1) void fused_all_kernel(
    const float* __restrict__ x,
    const float* __restrict__ Wih0f, const float* __restrict__ Whh0f,
    const float* __restrict__ bih0f, const float* __restrict__ bhh0f,
    const float* __restrict__ Wih0r, const float* __restrict__ Whh0r,
    const float* __restrict__ bih0r, const float* __restrict__ bhh0r,
    const float* __restrict__ Wih1f, const float* __restrict__ Whh1f,
    const float* __restrict__ bih1f, const float* __restrict__ bhh1f,
    const float* __restrict__ Wih1r,
    const float* __restrict__ bih1r, const float* __restrict__ bhh1r,
    const float* __restrict__ fcW, const float* __restrict__ fcb,
    float* __restrict__ out)
{
    const int g = threadIdx.x;
    const int b = blockIdx.x;

    __shared__ float xs[TT];
    __shared__ float cbuf[64][Hn];
    __shared__ float ckpt_h[8][Hn], ckpt_c[8][Hn];
    __shared__ float hr[40], h0s[80], hs1[40], zs[G4], red[40];

    for (int i = g; i < TT; i += G4) xs[i] = x[(size_t)b * TT + i];

    float wr[Hn], wf[Hn];
#pragma unroll
    for (int k = 0; k < Hn; ++k) wr[k] = Whh0r[g * Hn + k];
#pragma unroll
    for (int k = 0; k < Hn; ++k) wf[k] = Whh0f[g * Hn + k];
    const float wxr = Wih0r[g], br = bih0r[g] + bhh0r[g];
    const float wxf = Wih0f[g], bf = bih0f[g] + bhh0f[g];
    float w1i[72];
#pragma unroll
    for (int k = 0; k < 72; ++k) w1i[k] = Wih1f[g * 72 + k];
    float w1h[Hn];
#pragma unroll
    for (int k = 0; k < Hn; ++k) w1h[k] = Whh1f[g * Hn + k];
    const float b1 = bih1f[g] + bhh1f[g];

    if (g < Hn) hr[g] = 0.0f;
    float cr = 0.0f;
    __syncthreads();
    for (int s = 0; s < TT; ++s) {
        const int t = TT - 1 - s;
        if ((t & 63) == 63 && g < Hn) { ckpt_h[t >> 6][g] = hr[g]; ckpt_c[t >> 6][g] = cr; }
        float z0 = fmaf(xs[t], wxr, br), z1 = 0.f, z2 = 0.f, z3 = 0.f;
        DOT36(wr, hr, z0, z1, z2, z3);
        zs[g] = (z0 + z1) + (z2 + z3);
        __syncthreads();
        if (g < Hn) {
            float zi = zs[g], zf = zs[g + 36], zg = zs[g + 72], zo = zs[g + 108];
            cr = sigf(zf) * cr + sigf(zi) * tanh_fast(zg);
            hr[g] = sigf(zo) * tanh_fast(cr);
        }
        __syncthreads();
    }

    if (g < Hn) { h0s[g] = 0.0f; hs1[g] = 0.0f; }
    float c0 = 0.0f, c1 = 0.0f;
    __syncthreads();

    for (int m = 0; m < 8; ++m) {
        if (g < Hn) { hr[g] = ckpt_h[m][g]; cr = ckpt_c[m][g]; }
        __syncthreads();
        for (int j = 0; j < 64; ++j) {
            const int t = m * 64 + 63 - j;
            float z0 = fmaf(xs[t], wxr, br), z1 = 0.f, z2 = 0.f, z3 = 0.f;
            DOT36(wr, hr, z0, z1, z2, z3);
            zs[g] = (z0 + z1) + (z2 + z3);
            __syncthreads();
            if (g < Hn) {
                float zi = zs[g], zf = zs[g + 36], zg = zs[g + 72], zo = zs[g + 108];
                cr = sigf(zf) * cr + sigf(zi) * tanh_fast(zg);
                float h = sigf(zo) * tanh_fast(cr);
                hr[g] = h;
                cbuf[t & 63][g] = h;
            }
            __syncthreads();
        }
        for (int j = 0; j < 64; ++j) {
            const int t = m * 64 + j;
            float z0 = fmaf(xs[t], wxf, bf), z1 = 0.f, z2 = 0.f, z3 = 0.f;
            DOT36(wf, h0s, z0, z1, z2, z3);
            zs[g] = (z0 + z1) + (z2 + z3);
            __syncthreads();
            if (g < Hn) {
                float zi = zs[g], zf = zs[g + 36], zg = zs[g + 72], zo = zs[g + 108];
                c0 = sigf(zf) * c0 + sigf(zi) * tanh_fast(zg);
                h0s[g] = sigf(zo) * tanh_fast(c0);
            } else if (g < 72) {
                h0s[g] = cbuf[j][g - 36];
            }
            __syncthreads();
            float y0 = b1, y1 = 0.f, y2 = 0.f, y3 = 0.f;
            DOT72(w1i, h0s, y0, y1, y2, y3);
            DOT36(w1h, hs1, y0, y1, y2, y3);
            zs[g] = (y0 + y1) + (y2 + y3);
            __syncthreads();
            if (g < Hn) {
                float zi = zs[g], zf = zs[g + 36], zg = zs[g + 72], zo = zs[g + 108];
                c1 = sigf(zf) * c1 + sigf(zi) * tanh_fast(zg);
                hs1[g] = sigf(zo) * tanh_fast(c1);
            }
            __syncthreads();
        }
    }

    float zR = bih1r[g] + bhh1r[g];
#pragma unroll
    for (int k = 0; k < 72; ++k) zR = fmaf(Wih1r[g * 72 + k], h0s[k], zR);
    zs[g] = zR;
    __syncthreads();
    if (g < Hn) {
        float zi = zs[g], zg = zs[g + 72], zo = zs[g + 108];
        float c  = sigf(zi) * tanh_fast(zg);
        float hrv = sigf(zo) * tanh_fast(c);
        red[g] = fcW[36 + g] * hrv + fcW[g] * hs1[g];
    }
    __syncthreads();
    if (g == 0) {
        float s = fcb[0];
        for (int j = 0; j < Hn; ++j) s += red[j];
        out[b] = s;
    }
}

extern "C" void kernel_launch(void* const* d_in, const int* in_sizes, int n_in,
                              void* d_out, int out_size, void* d_ws, size_t ws_size,
                              hipStream_t stream)
{
    const float* x     = (const float*)d_in[0];
    const float* Wih0f = (const float*)d_in[1];
    const float* Whh0f = (const float*)d_in[2];
    const float* bih0f = (const float*)d_in[3];
    const float* bhh0f = (const float*)d_in[4];
    const float* Wih0r = (const float*)d_in[5];
    const float* Whh0r = (const float*)d_in[6];
    const float* bih0r = (const float*)d_in[7];
    const float* bhh0r = (const float*)d_in[8];
    const float* Wih1f = (const float*)d_in[9];
    const float* Whh1f = (const float*)d_in[10];
    const float* bih1f = (const float*)d_in[11];
    const float* bhh1f = (const float*)d_in[12];
    const float* Wih1r = (const float*)d_in[13];
    const float* bih1r = (const float*)d_in[15];
    const float* bhh1r = (const float*)d_in[16];
    const float* fcW   = (const float*)d_in[17];
    const float* fcb   = (const float*)d_in[18];

    const size_t need = (size_t)BB * TT * Hn * sizeof(float);   // 151 MB
    if (d_ws != nullptr && ws_size >= need) {
        float* h0r = (float*)d_ws;
        l0rev_kernel<<<BB / CH0, NT0, 0, stream>>>(x, Wih0r, Whh0r, bih0r, bhh0r, h0r);
        fused_fwd_kernel<<<BB / 2, NT1, 0, stream>>>(
            x, Wih0f, Whh0f, bih0f, bhh0f, Wih1f, Whh1f, bih1f, bhh1f,
            Wih1r, bih1r, bhh1r, fcW, fcb, h0r, (float*)d_out);
    } else {
        fused_all_kernel<<<BB, G4, 0, stream>>>(
            x, Wih0f, Whh0f, bih0f, bhh0f, Wih0r, Whh0r, bih0r, bhh0r,
            Wih1f, Whh1f, bih1f, bhh1f, Wih1r, bih1r, bhh1r, fcW, fcb,
            (float*)d_out);
    }
}

// Round 8
// 3644.566 us; speedup vs baseline: 1.0487x; 1.0487x over previous
//
#include <hip/hip_runtime.h>
#include <cstdint>

#define Hn 36
#define G4 144          // 4*H gate rows
#define TT 512
#define BB 2048

#define SG  4           // chains (subgroups) per block
#define NTF (SG * G4)   // 576 threads = 9 waves
#define WST 148         // fused weight-row stride (dw): 148%32=20 -> conflict-free b128
#define WST0 44         // l0rev weight-row stride: 44%32=12 -> conflict-free b128

__device__ __forceinline__ float sigf(float x) { return 1.0f / (1.0f + __expf(-x)); }
__device__ __forceinline__ float tanh_fast(float x) {
    float e = __expf(2.0f * x);          // exact +-1 limits via over/underflow
    return 1.0f - 2.0f / (e + 1.0f);
}

// array-based dots (fallback kernel only — unused when workspace is present)
#define DOT36(W, H, Z0, Z1, Z2, Z3)                        \
    do {                                                   \
        _Pragma("unroll") for (int _k = 0; _k < 9; ++_k) { \
            float4 hv = *(const float4*)&(H)[_k * 4];      \
            Z0 = fmaf((W)[_k * 4 + 0], hv.x, Z0);          \
            Z1 = fmaf((W)[_k * 4 + 1], hv.y, Z1);          \
            Z2 = fmaf((W)[_k * 4 + 2], hv.z, Z2);          \
            Z3 = fmaf((W)[_k * 4 + 3], hv.w, Z3);          \
        }                                                  \
    } while (0)

#define DOT72(W, H, Z0, Z1, Z2, Z3)                         \
    do {                                                    \
        _Pragma("unroll") for (int _k = 0; _k < 18; ++_k) { \
            float4 hv = *(const float4*)&(H)[_k * 4];       \
            Z0 = fmaf((W)[_k * 4 + 0], hv.x, Z0);           \
            Z1 = fmaf((W)[_k * 4 + 1], hv.y, Z1);           \
            Z2 = fmaf((W)[_k * 4 + 2], hv.z, Z2);           \
            Z3 = fmaf((W)[_k * 4 + 3], hv.w, Z3);           \
        }                                                   \
    } while (0)

// ======================= PRIMARY PATH (needs 151 MB ws) ======================
// Kernel 1: layer-0 reverse scan -> h0r (B, T, 36). Weights in LDS (36/row,
// stride 44 dw). One thread per (chain sg, gate row g).
__global__ __launch_bounds__(NTF) void l0rev_kernel(
    const float* __restrict__ x,
    const float* __restrict__ Wih, const float* __restrict__ Whh,
    const float* __restrict__ bih, const float* __restrict__ bhh,
    float* __restrict__ h0r)
{
    const int tid = threadIdx.x;
    const int sg  = tid / G4;
    const int g   = tid % G4;
    const int b   = blockIdx.x * SG + sg;

    __shared__ float wtab[G4 * WST0];   // 25.3 KB
    __shared__ float xs[SG][TT];        // 8 KB
    __shared__ float hs[SG][40];
    __shared__ float zsb[SG][WST];

    for (int i = tid; i < G4 * Hn; i += NTF)
        wtab[(i / Hn) * WST0 + (i % Hn)] = Whh[i];
    for (int i = g; i < TT; i += G4)
        xs[sg][i] = x[(size_t)b * TT + i];

    const float wx   = Wih[g];
    const float bias = bih[g] + bhh[g];

    if (g < 40) hs[sg][g] = 0.0f;
    float c = 0.0f;
    __syncthreads();

    const float* wr = &wtab[g * WST0];
    float* rrow = h0r + (size_t)b * TT * Hn;

    for (int s = 0; s < TT; ++s) {
        const int t = TT - 1 - s;
        float z0 = fmaf(xs[sg][t], wx, bias), z1 = 0.f, z2 = 0.f, z3 = 0.f;
#pragma unroll
        for (int kq = 0; kq < 9; ++kq) {
            float4 wq = *(const float4*)&wr[kq * 4];
            float4 hq = *(const float4*)&hs[sg][kq * 4];
            z0 = fmaf(wq.x, hq.x, z0); z1 = fmaf(wq.y, hq.y, z1);
            z2 = fmaf(wq.z, hq.z, z2); z3 = fmaf(wq.w, hq.w, z3);
        }
        zsb[sg][g] = (z0 + z1) + (z2 + z3);
        __syncthreads();
        if (g < Hn) {
            float zi = zsb[sg][g], zf = zsb[sg][g + 36], zg = zsb[sg][g + 72], zo = zsb[sg][g + 108];
            c = sigf(zf) * c + sigf(zi) * tanh_fast(zg);
            float h = sigf(zo) * tanh_fast(c);
            hs[sg][g] = h;
            rrow[(size_t)t * Hn + g] = h;
        }
        __syncthreads();
    }
}

// Kernel 2: fused L0-fwd + L1-fwd + single-step L1-rev + FC. Weights in LDS:
// row g holds [Whh0f(36) | Wih1f(72) | Whh1f(36)] at stride 148 dw.
__global__ __launch_bounds__(NTF) void fused_fwd_kernel(
    const float* __restrict__ x,
    const float* __restrict__ Wih0f, const float* __restrict__ Whh0f,
    const float* __restrict__ bih0f, const float* __restrict__ bhh0f,
    const float* __restrict__ Wih1f, const float* __restrict__ Whh1f,
    const float* __restrict__ bih1f, const float* __restrict__ bhh1f,
    const float* __restrict__ Wih1r,
    const float* __restrict__ bih1r, const float* __restrict__ bhh1r,
    const float* __restrict__ fcW, const float* __restrict__ fcb,
    const float* __restrict__ h0r,
    float* __restrict__ out)
{
    const int tid = threadIdx.x;
    const int sg  = tid / G4;
    const int g   = tid % G4;
    const int b   = blockIdx.x * SG + sg;

    __shared__ float wtab[G4 * WST];    // 85.2 KB
    __shared__ float xs[SG][TT];        // 8 KB
    __shared__ float h0s[SG][80];       // [h0f(36) | h0r(36) | pad]
    __shared__ float hs1[SG][40];
    __shared__ float zsb[SG][WST];
    __shared__ float red[SG][40];

    for (int i = tid; i < G4 * Hn; i += NTF)
        wtab[(i / Hn) * WST + (i % Hn)] = Whh0f[i];
    for (int i = tid; i < G4 * 72; i += NTF)
        wtab[(i / 72) * WST + 36 + (i % 72)] = Wih1f[i];
    for (int i = tid; i < G4 * Hn; i += NTF)
        wtab[(i / Hn) * WST + 108 + (i % Hn)] = Whh1f[i];
    for (int i = g; i < TT; i += G4)
        xs[sg][i] = x[(size_t)b * TT + i];

    const float wx0 = Wih0f[g];
    const float b0  = bih0f[g] + bhh0f[g];
    const float b1  = bih1f[g] + bhh1f[g];

    if (g < 80) h0s[sg][g] = 0.0f;
    if (g < 40) hs1[sg][g] = 0.0f;
    float c0 = 0.0f, c1 = 0.0f;

    const float* rrow = h0r + (size_t)b * TT * Hn;
    float rv = (g >= 36 && g < 72) ? rrow[g - 36] : 0.0f;   // h0r(t=0)
    __syncthreads();

    const float* wr = &wtab[g * WST];

    for (int t = 0; t < TT; ++t) {
        // ---- phase A: layer-0 forward ----
        float z0 = fmaf(xs[sg][t], wx0, b0), z1 = 0.f, z2 = 0.f, z3 = 0.f;
#pragma unroll
        for (int kq = 0; kq < 9; ++kq) {
            float4 wq = *(const float4*)&wr[kq * 4];
            float4 hq = *(const float4*)&h0s[sg][kq * 4];
            z0 = fmaf(wq.x, hq.x, z0); z1 = fmaf(wq.y, hq.y, z1);
            z2 = fmaf(wq.z, hq.z, z2); z3 = fmaf(wq.w, hq.w, z3);
        }
        zsb[sg][g] = (z0 + z1) + (z2 + z3);
        __syncthreads();
        if (g < Hn) {
            float zi = zsb[sg][g], zf = zsb[sg][g + 36], zg = zsb[sg][g + 72], zo = zsb[sg][g + 108];
            c0 = sigf(zf) * c0 + sigf(zi) * tanh_fast(zg);
            h0s[sg][g] = sigf(zo) * tanh_fast(c0);
        } else if (g < 72) {
            h0s[sg][g] = rv;                     // h0r(t), prefetched
        }
        __syncthreads();
        if (g >= 36 && g < 72 && t + 1 < TT)     // prefetch h0r(t+1)
            rv = rrow[(size_t)(t + 1) * Hn + (g - 36)];

        // ---- phase B: layer-1 forward ----
        z0 = b1; z1 = 0.f; z2 = 0.f; z3 = 0.f;
#pragma unroll
        for (int kq = 0; kq < 18; ++kq) {
            float4 wq = *(const float4*)&wr[36 + kq * 4];
            float4 hq = *(const float4*)&h0s[sg][kq * 4];
            z0 = fmaf(wq.x, hq.x, z0); z1 = fmaf(wq.y, hq.y, z1);
            z2 = fmaf(wq.z, hq.z, z2); z3 = fmaf(wq.w, hq.w, z3);
        }
#pragma unroll
        for (int kq = 0; kq < 9; ++kq) {
            float4 wq = *(const float4*)&wr[108 + kq * 4];
            float4 hq = *(const float4*)&hs1[sg][kq * 4];
            z0 = fmaf(wq.x, hq.x, z0); z1 = fmaf(wq.y, hq.y, z1);
            z2 = fmaf(wq.z, hq.z, z2); z3 = fmaf(wq.w, hq.w, z3);
        }
        zsb[sg][g] = (z0 + z1) + (z2 + z3);
        __syncthreads();
        if (g < Hn) {
            float zi = zsb[sg][g], zf = zsb[sg][g + 36], zg = zsb[sg][g + 72], zo = zsb[sg][g + 108];
            c1 = sigf(zf) * c1 + sigf(zi) * tanh_fast(zg);
            hs1[sg][g] = sigf(zo) * tanh_fast(c1);
        }
        __syncthreads();
    }

    // ---- tail: L1 reverse single step at t=T-1 (h0=c0=0) + FC ----
    float zR = bih1r[g] + bhh1r[g];
#pragma unroll
    for (int k = 0; k < 72; ++k) zR = fmaf(Wih1r[g * 72 + k], h0s[sg][k], zR);
    zsb[sg][g] = zR;
    __syncthreads();
    if (g < Hn) {
        float zi = zsb[sg][g], zg = zsb[sg][g + 72], zo = zsb[sg][g + 108];
        float c  = sigf(zi) * tanh_fast(zg);     // c0=0: forget term vanishes
        float hr = sigf(zo) * tanh_fast(c);
        red[sg][g] = fcW[36 + g] * hr + fcW[g] * hs1[sg][g];
    }
    __syncthreads();
    if (g == 0) {
        float s = fcb[0];
        for (int j = 0; j < Hn; ++j) s += red[sg][j];
        out[b] = s;
    }
}

// ================= FALLBACK PATH (zero workspace, ckpt/recompute) ============
// Unused when the harness provides >=151MB workspace (it does today).
__global__ __launch_bounds__(G4, 1) void fused_all_kernel(
    const float* __restrict__ x,
    const float* __restrict__ Wih0f, const float* __restrict__ Whh0f,
    const float* __restrict__ bih0f, const float* __restrict__ bhh0f,
    const float* __restrict__ Wih0r, const float* __restrict__ Whh0r,
    const float* __restrict__ bih0r, const float* __restrict__ bhh0r,
    const float* __restrict__ Wih1f, const float* __restrict__ Whh1f,
    const float* __restrict__ bih1f, const float* __restrict__ bhh1f,
    const float* __restrict__ Wih1r,
    const float* __restrict__ bih1r, const float* __restrict__ bhh1r,
    const float* __restrict__ fcW, const float* __restrict__ fcb,
    float* __restrict__ out)
{
    const int g = threadIdx.x;
    const int b = blockIdx.x;

    __shared__ float xs[TT];
    __shared__ float cbuf[64][Hn];
    __shared__ float ckpt_h[8][Hn], ckpt_c[8][Hn];
    __shared__ float hr[40], h0s[80], hs1[40], zs[G4], red[40];

    for (int i = g; i < TT; i += G4) xs[i] = x[(size_t)b * TT + i];

    float wr[Hn], wf[Hn];
#pragma unroll
    for (int k = 0; k < Hn; ++k) wr[k] = Whh0r[g * Hn + k];
#pragma unroll
    for (int k = 0; k < Hn; ++k) wf[k] = Whh0f[g * Hn + k];
    const float wxr = Wih0r[g], br = bih0r[g] + bhh0r[g];
    const float wxf = Wih0f[g], bf = bih0f[g] + bhh0f[g];
    float w1i[72];
#pragma unroll
    for (int k = 0; k < 72; ++k) w1i[k] = Wih1f[g * 72 + k];
    float w1h[Hn];
#pragma unroll
    for (int k = 0; k < Hn; ++k) w1h[k] = Whh1f[g * Hn + k];
    const float b1 = bih1f[g] + bhh1f[g];

    if (g < Hn) hr[g] = 0.0f;
    float cr = 0.0f;
    __syncthreads();
    for (int s = 0; s < TT; ++s) {
        const int t = TT - 1 - s;
        if ((t & 63) == 63 && g < Hn) { ckpt_h[t >> 6][g] = hr[g]; ckpt_c[t >> 6][g] = cr; }
        float z0 = fmaf(xs[t], wxr, br), z1 = 0.f, z2 = 0.f, z3 = 0.f;
        DOT36(wr, hr, z0, z1, z2, z3);
        zs[g] = (z0 + z1) + (z2 + z3);
        __syncthreads();
        if (g < Hn) {
            float zi = zs[g], zf = zs[g + 36], zg = zs[g + 72], zo = zs[g + 108];
            cr = sigf(zf) * cr + sigf(zi) * tanh_fast(zg);
            hr[g] = sigf(zo) * tanh_fast(cr);
        }
        __syncthreads();
    }

    if (g < Hn) { h0s[g] = 0.0f; hs1[g] = 0.0f; }
    float c0 = 0.0f, c1 = 0.0f;
    __syncthreads();

    for (int m = 0; m < 8; ++m) {
        if (g < Hn) { hr[g] = ckpt_h[m][g]; cr = ckpt_c[m][g]; }
        __syncthreads();
        for (int j = 0; j < 64; ++j) {
            const int t = m * 64 + 63 - j;
            float z0 = fmaf(xs[t], wxr, br), z1 = 0.f, z2 = 0.f, z3 = 0.f;
            DOT36(wr, hr, z0, z1, z2, z3);
            zs[g] = (z0 + z1) + (z2 + z3);
            __syncthreads();
            if (g < Hn) {
                float zi = zs[g], zf = zs[g + 36], zg = zs[g + 72], zo = zs[g + 108];
                cr = sigf(zf) * cr + sigf(zi) * tanh_fast(zg);
                float h = sigf(zo) * tanh_fast(cr);
                hr[g] = h;
                cbuf[t & 63][g] = h;
            }
            __syncthreads();
        }
        for (int j = 0; j < 64; ++j) {
            const int t = m * 64 + j;
            float z0 = fmaf(xs[t], wxf, bf), z1 = 0.f, z2 = 0.f, z3 = 0.f;
            DOT36(wf, h0s, z0, z1, z2, z3);
            zs[g] = (z0 + z1) + (z2 + z3);
            __syncthreads();
            if (g < Hn) {
                float zi = zs[g], zf = zs[g + 36], zg = zs[g + 72], zo = zs[g + 108];
                c0 = sigf(zf) * c0 + sigf(zi) * tanh_fast(zg);
                h0s[g] = sigf(zo) * tanh_fast(c0);
            } else if (g < 72) {
                h0s[g] = cbuf[j][g - 36];
            }
            __syncthreads();
            float y0 = b1, y1 = 0.f, y2 = 0.f, y3 = 0.f;
            DOT72(w1i, h0s, y0, y1, y2, y3);
            DOT36(w1h, hs1, y0, y1, y2, y3);
            zs[g] = (y0 + y1) + (y2 + y3);
            __syncthreads();
            if (g < Hn) {
                float zi = zs[g], zf = zs[g + 36], zg = zs[g + 72], zo = zs[g + 108];
                c1 = sigf(zf) * c1 + sigf(zi) * tanh_fast(zg);
                hs1[g] = sigf(zo) * tanh_fast(c1);
            }
            __syncthreads();
        }
    }

    float zR = bih1r[g] + bhh1r[g];
#pragma unroll
    for (int k = 0; k < 72; ++k) zR = fmaf(Wih1r[g * 72 + k], h0s[k], zR);
    zs[g] = zR;
    __syncthreads();
    if (g < Hn) {
        float zi = zs[g], zg = zs[g + 72], zo = zs[g + 108];
        float c  = sigf(zi) * tanh_fast(zg);
        float hrv = sigf(zo) * tanh_fast(c);
        red[g] = fcW[36 + g] * hrv + fcW[g] * hs1[g];
    }
    __syncthreads();
    if (g == 0) {
        float s = fcb[0];
        for (int j = 0; j < Hn; ++j) s += red[j];
        out[b] = s;
    }
}

extern "C" void kernel_launch(void* const* d_in, const int* in_sizes, int n_in,
                              void* d_out, int out_size, void* d_ws, size_t ws_size,
                              hipStream_t stream)
{
    const float* x     = (const float*)d_in[0];
    const float* Wih0f = (const float*)d_in[1];
    const float* Whh0f = (const float*)d_in[2];
    const float* bih0f = (const float*)d_in[3];
    const float* bhh0f = (const float*)d_in[4];
    const float* Wih0r = (const float*)d_in[5];
    const float* Whh0r = (const float*)d_in[6];
    const float* bih0r = (const float*)d_in[7];
    const float* bhh0r = (const float*)d_in[8];
    const float* Wih1f = (const float*)d_in[9];
    const float* Whh1f = (const float*)d_in[10];
    const float* bih1f = (const float*)d_in[11];
    const float* bhh1f = (const float*)d_in[12];
    const float* Wih1r = (const float*)d_in[13];
    const float* bih1r = (const float*)d_in[15];
    const float* bhh1r = (const float*)d_in[16];
    const float* fcW   = (const float*)d_in[17];
    const float* fcb   = (const float*)d_in[18];

    const size_t need = (size_t)BB * TT * Hn * sizeof(float);   // 151 MB
    if (d_ws != nullptr && ws_size >= need) {
        float* h0r = (float*)d_ws;
        l0rev_kernel<<<BB / SG, NTF, 0, stream>>>(x, Wih0r, Whh0r, bih0r, bhh0r, h0r);
        fused_fwd_kernel<<<BB / SG, NTF, 0, stream>>>(
            x, Wih0f, Whh0f, bih0f, bhh0f, Wih1f, Whh1f, bih1f, bhh1f,
            Wih1r, bih1r, bhh1r, fcW, fcb, h0r, (float*)d_out);
    } else {
        fused_all_kernel<<<BB, G4, 0, stream>>>(
            x, Wih0f, Whh0f, bih0f, bhh0f, Wih0r, Whh0r, bih0r, bhh0r,
            Wih1f, Whh1f, bih1f, bhh1f, Wih1r, bih1r, bhh1r, fcW, fcb,
            (float*)d_out);
    }
}

// Round 9
// 2762.682 us; speedup vs baseline: 1.3834x; 1.3192x over previous
//
#include <hip/hip_runtime.h>
#include <cstdint>

#define Hn 36
#define G4 144          // 4*H gate rows
#define TT 512
#define BB 2048
#define CHUNK 1024      // chains per chunk (2 chunks reuse the same ws buffers)

__device__ __forceinline__ float sigf(float x) { return 1.0f / (1.0f + __expf(-x)); }
__device__ __forceinline__ float tanh_fast(float x) {
    float e = __expf(2.0f * x);          // exact +-1 limits via over/underflow
    return 1.0f - 2.0f / (e + 1.0f);
}

// ---- named-register weight quads (scalar asm ties; proven no-spill at 36 floats)
#define REP9(M, P)  M(P,0) M(P,1) M(P,2) M(P,3) M(P,4) M(P,5) M(P,6) M(P,7) M(P,8)
#define DECLQ(P, i) float P##i##x, P##i##y, P##i##z, P##i##w;
#define LOADQ(P, i) { float4 _t = wp[i]; P##i##x = _t.x; P##i##y = _t.y; P##i##z = _t.z; P##i##w = _t.w; }
#define PINQ(P, i)  asm volatile("" : "+v"(P##i##x), "+v"(P##i##y), "+v"(P##i##z), "+v"(P##i##w));
#define FMAQ(P, i)                                                        \
    {  float4 hv = *(const float4*)&hb[(i) * 4];                          \
       z0 = fmaf(P##i##x, hv.x, z0); z1 = fmaf(P##i##y, hv.y, z1);        \
       z2 = fmaf(P##i##z, hv.z, z2); z3 = fmaf(P##i##w, hv.w, z3); }

// array-based dots (fallback kernel only)
#define DOT36(W, H, Z0, Z1, Z2, Z3)                        \
    do {                                                   \
        _Pragma("unroll") for (int _k = 0; _k < 9; ++_k) { \
            float4 hv = *(const float4*)&(H)[_k * 4];      \
            Z0 = fmaf((W)[_k * 4 + 0], hv.x, Z0);          \
            Z1 = fmaf((W)[_k * 4 + 1], hv.y, Z1);          \
            Z2 = fmaf((W)[_k * 4 + 2], hv.z, Z2);          \
            Z3 = fmaf((W)[_k * 4 + 3], hv.w, Z3);          \
        }                                                  \
    } while (0)

#define DOT72(W, H, Z0, Z1, Z2, Z3)                         \
    do {                                                    \
        _Pragma("unroll") for (int _k = 0; _k < 18; ++_k) { \
            float4 hv = *(const float4*)&(H)[_k * 4];       \
            Z0 = fmaf((W)[_k * 4 + 0], hv.x, Z0);           \
            Z1 = fmaf((W)[_k * 4 + 1], hv.y, Z1);           \
            Z2 = fmaf((W)[_k * 4 + 2], hv.z, Z2);           \
            Z3 = fmaf((W)[_k * 4 + 3], hv.w, Z3);           \
        }                                                   \
    } while (0)

// =================== K1: layer-0 scan, BOTH dirs (blockIdx.y) ================
// 36 reg-weights/thread (proven no-spill). Writes h0f / h0r chunk buffers.
#define SG1 4
#define NTK1 (SG1 * G4)   // 576
__global__ __launch_bounds__(NTK1) void l0scan_kernel(
    const float* __restrict__ x,
    const float* __restrict__ Wih0f, const float* __restrict__ Whh0f,
    const float* __restrict__ bih0f, const float* __restrict__ bhh0f,
    const float* __restrict__ Wih0r, const float* __restrict__ Whh0r,
    const float* __restrict__ bih0r, const float* __restrict__ bhh0r,
    float* __restrict__ h0f, float* __restrict__ h0r, int base)
{
    const int tid = threadIdx.x;
    const int cc  = tid / G4;
    const int g   = tid % G4;
    const int dir = blockIdx.y;
    const int cl  = blockIdx.x * SG1 + cc;   // chunk-local chain
    const int b   = base + cl;

    const float* Wih = dir ? Wih0r : Wih0f;
    const float* Whh = dir ? Whh0r : Whh0f;
    const float* bih = dir ? bih0r : bih0f;
    const float* bhh = dir ? bhh0r : bhh0f;

    __shared__ float xs[SG1][TT];
    __shared__ float hs[SG1][40];
    __shared__ float zs[SG1][G4];

    for (int i = g; i < TT; i += G4) xs[cc][i] = x[(size_t)b * TT + i];

    REP9(DECLQ, R)
    {
        const float4* wp = (const float4*)(Whh + g * Hn);   // 144B rows, 16B-aligned
        REP9(LOADQ, R)
    }
    float wx   = Wih[g];
    float bias = bih[g] + bhh[g];
    REP9(PINQ, R)
    asm volatile("" : "+v"(wx), "+v"(bias));

    if (g < 40) hs[cc][g] = 0.0f;
    float c = 0.0f;
    __syncthreads();

    float* dst = (dir ? h0r : h0f) + (size_t)cl * TT * Hn;

    for (int s = 0; s < TT; ++s) {
        const int t = dir ? (TT - 1 - s) : s;
        float z0 = fmaf(xs[cc][t], wx, bias), z1 = 0.f, z2 = 0.f, z3 = 0.f;
        {
            const float* hb = hs[cc];
            REP9(FMAQ, R)
        }
        zs[cc][g] = (z0 + z1) + (z2 + z3);
        __syncthreads();
        if (g < Hn) {
            float zi = zs[cc][g], zf = zs[cc][g + 36], zg = zs[cc][g + 72], zo = zs[cc][g + 108];
            c = sigf(zf) * c + sigf(zi) * tanh_fast(zg);
            float h = sigf(zo) * tanh_fast(c);
            hs[cc][g] = h;
            dst[(size_t)t * Hn + g] = h;
        }
        __syncthreads();
    }
}

// ====== K2: layer-1 forward scan (3-way k-split, 36 reg-wts each) + tail =====
// gp0: Wih1f[:, :36] . h0f ; gp1: Wih1f[:, 36:] . h0r ; gp2: Whh1f . h1.
// h0f/h0r streamed from global with depth-1.5 prefetch. 2 barriers/step.
#define NTL 432
__global__ __launch_bounds__(NTL) void l1scan_kernel(
    const float* __restrict__ h0f, const float* __restrict__ h0r,
    const float* __restrict__ Wih1f, const float* __restrict__ Whh1f,
    const float* __restrict__ bih1f, const float* __restrict__ bhh1f,
    const float* __restrict__ Wih1r,
    const float* __restrict__ bih1r, const float* __restrict__ bhh1r,
    const float* __restrict__ fcW, const float* __restrict__ fcb,
    float* __restrict__ out, int base)
{
    const int tid = threadIdx.x;
    const int gp  = tid / G4;    // 0,1,2
    const int g   = tid % G4;
    const int cl  = blockIdx.x;
    const int b   = base + cl;

    __shared__ float h0fs[40], h0rs[40], hs1[40];
    __shared__ float zp[3][160];
    __shared__ float red[40];

    const float* wp0 = (gp == 0) ? (Wih1f + g * 72)
                     : (gp == 1) ? (Wih1f + g * 72 + 36)
                                 : (Whh1f + g * Hn);
    REP9(DECLQ, W)
    {
        const float4* wp = (const float4*)wp0;   // offsets 0/144B/144B-rows: 16B-aligned
        REP9(LOADQ, W)
    }
    float bsum = (gp == 0) ? (bih1f[g] + bhh1f[g]) : 0.0f;
    REP9(PINQ, W)
    asm volatile("" : "+v"(bsum));

    const float* srow = ((gp == 0) ? h0f : h0r) + (size_t)cl * TT * Hn;
    const bool pf = (gp < 2) && (g < Hn);

    if (pf) ((gp == 0) ? h0fs : h0rs)[g] = srow[g];   // t=0
    if (gp == 2 && g < 40) hs1[g] = 0.0f;
    float c1  = 0.0f;
    float rvN = pf ? srow[Hn + g] : 0.0f;             // t=1
    __syncthreads();

    for (int t = 0; t < TT; ++t) {
        // issue prefetch for t+2 early (hidden under dot + barrier + combine)
        float rv2 = (pf && t + 2 < TT) ? srow[(size_t)(t + 2) * Hn + g] : 0.0f;

        const float* hb = (gp == 0) ? h0fs : (gp == 1) ? h0rs : hs1;
        float z0 = bsum, z1 = 0.f, z2 = 0.f, z3 = 0.f;
        REP9(FMAQ, W)
        zp[gp][g] = (z0 + z1) + (z2 + z3);
        __syncthreads();

        if (gp == 2) {
            if (g < Hn) {
                float zi = zp[0][g]       + zp[1][g]       + zp[2][g];
                float zf = zp[0][g + 36]  + zp[1][g + 36]  + zp[2][g + 36];
                float zg = zp[0][g + 72]  + zp[1][g + 72]  + zp[2][g + 72];
                float zo = zp[0][g + 108] + zp[1][g + 108] + zp[2][g + 108];
                c1 = sigf(zf) * c1 + sigf(zi) * tanh_fast(zg);
                hs1[g] = sigf(zo) * tanh_fast(c1);
            }
        } else if (pf && t + 1 < TT) {
            ((gp == 0) ? h0fs : h0rs)[g] = rvN;       // advance h0 stream to t+1
        }
        rvN = rv2;
        __syncthreads();
    }

    // ---- tail: L1 reverse single step at t=T-1 (h0=c0=0) + FC ----
    float zR = 0.0f;
    if (gp == 0) {
        const float* wr = Wih1r + g * 72;
#pragma unroll
        for (int k = 0; k < Hn; ++k) zR = fmaf(wr[k], h0fs[k], zR);
        zR += bih1r[g] + bhh1r[g];
    } else if (gp == 1) {
        const float* wr = Wih1r + g * 72 + 36;
#pragma unroll
        for (int k = 0; k < Hn; ++k) zR = fmaf(wr[k], h0rs[k], zR);
    }
    zp[gp][g] = zR;
    __syncthreads();
    if (tid < Hn) {
        float zi = zp[0][tid]       + zp[1][tid];
        float zg = zp[0][tid + 72]  + zp[1][tid + 72];
        float zo = zp[0][tid + 108] + zp[1][tid + 108];
        float c  = sigf(zi) * tanh_fast(zg);     // c0=0: forget term vanishes
        float hR = sigf(zo) * tanh_fast(c);
        red[tid] = fcW[36 + tid] * hR + fcW[tid] * hs1[tid];
    }
    __syncthreads();
    if (tid == 0) {
        float s2 = fcb[0];
        for (int j = 0; j < Hn; ++j) s2 += red[j];
        out[b] = s2;
    }
}

// ================= FALLBACK PATH (zero workspace, ckpt/recompute) ============
__global__ __launch_bounds__(G4, 1) void fused_all_kernel(
    const float* __restrict__ x,
    const float* __restrict__ Wih0f, const float* __restrict__ Whh0f,
    const float* __restrict__ bih0f, const float* __restrict__ bhh0f,
    const float* __restrict__ Wih0r, const float* __restrict__ Whh0r,
    const float* __restrict__ bih0r, const float* __restrict__ bhh0r,
    const float* __restrict__ Wih1f, const float* __restrict__ Whh1f,
    const float* __restrict__ bih1f, const float* __restrict__ bhh1f,
    const float* __restrict__ Wih1r,
    const float* __restrict__ bih1r, const float* __restrict__ bhh1r,
    const float* __restrict__ fcW, const float* __restrict__ fcb,
    float* __restrict__ out)
{
    const int g = threadIdx.x;
    const int b = blockIdx.x;

    __shared__ float xs[TT];
    __shared__ float cbuf[64][Hn];
    __shared__ float ckpt_h[8][Hn], ckpt_c[8][Hn];
    __shared__ float hr[40], h0s[80], hs1[40], zs[G4], red[40];

    for (int i = g; i < TT; i += G4) xs[i] = x[(size_t)b * TT + i];

    float wr[Hn], wf[Hn];
#pragma unroll
    for (int k = 0; k < Hn; ++k) wr[k] = Whh0r[g * Hn + k];
#pragma unroll
    for (int k = 0; k < Hn; ++k) wf[k] = Whh0f[g * Hn + k];
    const float wxr = Wih0r[g], br = bih0r[g] + bhh0r[g];
    const float wxf = Wih0f[g], bf = bih0f[g] + bhh0f[g];
    float w1i[72];
#pragma unroll
    for (int k = 0; k < 72; ++k) w1i[k] = Wih1f[g * 72 + k];
    float w1h[Hn];
#pragma unroll
    for (int k = 0; k < Hn; ++k) w1h[k] = Whh1f[g * Hn + k];
    const float b1 = bih1f[g] + bhh1f[g];

    if (g < Hn) hr[g] = 0.0f;
    float cr = 0.0f;
    __syncthreads();
    for (int s = 0; s < TT; ++s) {
        const int t = TT - 1 - s;
        if ((t & 63) == 63 && g < Hn) { ckpt_h[t >> 6][g] = hr[g]; ckpt_c[t >> 6][g] = cr; }
        float z0 = fmaf(xs[t], wxr, br), z1 = 0.f, z2 = 0.f, z3 = 0.f;
        DOT36(wr, hr, z0, z1, z2, z3);
        zs[g] = (z0 + z1) + (z2 + z3);
        __syncthreads();
        if (g < Hn) {
            float zi = zs[g], zf = zs[g + 36], zg = zs[g + 72], zo = zs[g + 108];
            cr = sigf(zf) * cr + sigf(zi) * tanh_fast(zg);
            hr[g] = sigf(zo) * tanh_fast(cr);
        }
        __syncthreads();
    }

    if (g < Hn) { h0s[g] = 0.0f; hs1[g] = 0.0f; }
    float c0 = 0.0f, c1 = 0.0f;
    __syncthreads();

    for (int m = 0; m < 8; ++m) {
        if (g < Hn) { hr[g] = ckpt_h[m][g]; cr = ckpt_c[m][g]; }
        __syncthreads();
        for (int j = 0; j < 64; ++j) {
            const int t = m * 64 + 63 - j;
            float z0 = fmaf(xs[t], wxr, br), z1 = 0.f, z2 = 0.f, z3 = 0.f;
            DOT36(wr, hr, z0, z1, z2, z3);
            zs[g] = (z0 + z1) + (z2 + z3);
            __syncthreads();
            if (g < Hn) {
                float zi = zs[g], zf = zs[g + 36], zg = zs[g + 72], zo = zs[g + 108];
                cr = sigf(zf) * cr + sigf(zi) * tanh_fast(zg);
                float h = sigf(zo) * tanh_fast(cr);
                hr[g] = h;
                cbuf[t & 63][g] = h;
            }
            __syncthreads();
        }
        for (int j = 0; j < 64; ++j) {
            const int t = m * 64 + j;
            float z0 = fmaf(xs[t], wxf, bf), z1 = 0.f, z2 = 0.f, z3 = 0.f;
            DOT36(wf, h0s, z0, z1, z2, z3);
            zs[g] = (z0 + z1) + (z2 + z3);
            __syncthreads();
            if (g < Hn) {
                float zi = zs[g], zf = zs[g + 36], zg = zs[g + 72], zo = zs[g + 108];
                c0 = sigf(zf) * c0 + sigf(zi) * tanh_fast(zg);
                h0s[g] = sigf(zo) * tanh_fast(c0);
            } else if (g < 72) {
                h0s[g] = cbuf[j][g - 36];
            }
            __syncthreads();
            float y0 = b1, y1 = 0.f, y2 = 0.f, y3 = 0.f;
            DOT72(w1i, h0s, y0, y1, y2, y3);
            DOT36(w1h, hs1, y0, y1, y2, y3);
            zs[g] = (y0 + y1) + (y2 + y3);
            __syncthreads();
            if (g < Hn) {
                float zi = zs[g], zf = zs[g + 36], zg = zs[g + 72], zo = zs[g + 108];
                c1 = sigf(zf) * c1 + sigf(zi) * tanh_fast(zg);
                hs1[g] = sigf(zo) * tanh_fast(c1);
            }
            __syncthreads();
        }
    }

    float zR = bih1r[g] + bhh1r[g];
#pragma unroll
    for (int k = 0; k < 72; ++k) zR = fmaf(Wih1r[g * 72 + k], h0s[k], zR);
    zs[g] = zR;
    __syncthreads();
    if (g < Hn) {
        float zi = zs[g], zg = zs[g + 72], zo = zs[g + 108];
        float c  = sigf(zi) * tanh_fast(zg);
        float hrv = sigf(zo) * tanh_fast(c);
        red[g] = fcW[36 + g] * hrv + fcW[g] * hs1[g];
    }
    __syncthreads();
    if (g == 0) {
        float s = fcb[0];
        for (int j = 0; j < Hn; ++j) s += red[j];
        out[b] = s;
    }
}

extern "C" void kernel_launch(void* const* d_in, const int* in_sizes, int n_in,
                              void* d_out, int out_size, void* d_ws, size_t ws_size,
                              hipStream_t stream)
{
    const float* x     = (const float*)d_in[0];
    const float* Wih0f = (const float*)d_in[1];
    const float* Whh0f = (const float*)d_in[2];
    const float* bih0f = (const float*)d_in[3];
    const float* bhh0f = (const float*)d_in[4];
    const float* Wih0r = (const float*)d_in[5];
    const float* Whh0r = (const float*)d_in[6];
    const float* bih0r = (const float*)d_in[7];
    const float* bhh0r = (const float*)d_in[8];
    const float* Wih1f = (const float*)d_in[9];
    const float* Whh1f = (const float*)d_in[10];
    const float* bih1f = (const float*)d_in[11];
    const float* bhh1f = (const float*)d_in[12];
    const float* Wih1r = (const float*)d_in[13];
    const float* bih1r = (const float*)d_in[15];
    const float* bhh1r = (const float*)d_in[16];
    const float* fcW   = (const float*)d_in[17];
    const float* fcb   = (const float*)d_in[18];

    const size_t chunk_elems = (size_t)CHUNK * TT * Hn;          // 18.9M floats
    const size_t need = 2 * chunk_elems * sizeof(float);         // 151 MB
    if (d_ws != nullptr && ws_size >= need) {
        float* h0f = (float*)d_ws;
        float* h0r = h0f + chunk_elems;
        for (int chunk = 0; chunk < BB / CHUNK; ++chunk) {
            const int base = chunk * CHUNK;
            l0scan_kernel<<<dim3(CHUNK / SG1, 2), NTK1, 0, stream>>>(
                x, Wih0f, Whh0f, bih0f, bhh0f, Wih0r, Whh0r, bih0r, bhh0r,
                h0f, h0r, base);
            l1scan_kernel<<<CHUNK, NTL, 0, stream>>>(
                h0f, h0r, Wih1f, Whh1f, bih1f, bhh1f,
                Wih1r, bih1r, bhh1r, fcW, fcb, (float*)d_out, base);
        }
    } else {
        fused_all_kernel<<<BB, G4, 0, stream>>>(
            x, Wih0f, Whh0f, bih0f, bhh0f, Wih0r, Whh0r, bih0r, bhh0r,
            Wih1f, Whh1f, bih1f, bhh1f, Wih1r, bih1r, bhh1r, fcW, fcb,
            (float*)d_out);
    }
}

// Round 10
// 2679.938 us; speedup vs baseline: 1.4261x; 1.0309x over previous
//
#include <hip/hip_runtime.h>
#include <cstdint>

#define Hn 36
#define G4 144          // 4*H gate rows
#define TT 512
#define BB 2048

__device__ __forceinline__ float sigf(float x) { return 1.0f / (1.0f + __expf(-x)); }
__device__ __forceinline__ float tanh_fast(float x) {
    float e = __expf(2.0f * x);          // exact +-1 limits via over/underflow
    return 1.0f - 2.0f / (e + 1.0f);
}

// ---- named-register weight quads (36 floats = proven no-spill quantum) ----
#define REP9(M, P)  M(P,0) M(P,1) M(P,2) M(P,3) M(P,4) M(P,5) M(P,6) M(P,7) M(P,8)
#define DECLQ(P, i) float P##i##x, P##i##y, P##i##z, P##i##w;
#define LOADQ(P, i) { float4 _t = wp[i]; P##i##x = _t.x; P##i##y = _t.y; P##i##z = _t.z; P##i##w = _t.w; }
#define PINQ(P, i)  asm volatile("" : "+v"(P##i##x), "+v"(P##i##y), "+v"(P##i##z), "+v"(P##i##w));
#define FMAQ(P, i)                                                        \
    {  float4 hv = *(const float4*)&hb[(i) * 4];                          \
       z0 = fmaf(P##i##x, hv.x, z0); z1 = fmaf(P##i##y, hv.y, z1);        \
       z2 = fmaf(P##i##z, hv.z, z2); z3 = fmaf(P##i##w, hv.w, z3); }

// array-based dots (fallback kernel only)
#define DOT36(W, H, Z0, Z1, Z2, Z3)                        \
    do {                                                   \
        _Pragma("unroll") for (int _k = 0; _k < 9; ++_k) { \
            float4 hv = *(const float4*)&(H)[_k * 4];      \
            Z0 = fmaf((W)[_k * 4 + 0], hv.x, Z0);          \
            Z1 = fmaf((W)[_k * 4 + 1], hv.y, Z1);          \
            Z2 = fmaf((W)[_k * 4 + 2], hv.z, Z2);          \
            Z3 = fmaf((W)[_k * 4 + 3], hv.w, Z3);          \
        }                                                  \
    } while (0)

#define DOT72(W, H, Z0, Z1, Z2, Z3)                         \
    do {                                                    \
        _Pragma("unroll") for (int _k = 0; _k < 18; ++_k) { \
            float4 hv = *(const float4*)&(H)[_k * 4];       \
            Z0 = fmaf((W)[_k * 4 + 0], hv.x, Z0);           \
            Z1 = fmaf((W)[_k * 4 + 1], hv.y, Z1);           \
            Z2 = fmaf((W)[_k * 4 + 2], hv.z, Z2);           \
            Z3 = fmaf((W)[_k * 4 + 3], hv.w, Z3);           \
        }                                                   \
    } while (0)

// ============ K1: layer-0 REVERSE scan, full batch -> h0r (151 MB ws) ========
#define SG1 4
#define NTK1 (SG1 * G4)   // 576
__global__ __launch_bounds__(NTK1) void l0rev_kernel(
    const float* __restrict__ x,
    const float* __restrict__ Wih, const float* __restrict__ Whh,
    const float* __restrict__ bih, const float* __restrict__ bhh,
    float* __restrict__ h0r)
{
    const int tid = threadIdx.x;
    const int cc  = tid / G4;
    const int g   = tid % G4;
    const int b   = blockIdx.x * SG1 + cc;

    __shared__ float xs[SG1][TT];
    __shared__ float hs[SG1][40];
    __shared__ float zs[SG1][G4];

    for (int i = g; i < TT; i += G4) xs[cc][i] = x[(size_t)b * TT + i];

    REP9(DECLQ, R)
    {
        const float4* wp = (const float4*)(Whh + g * Hn);
        REP9(LOADQ, R)
    }
    float wx   = Wih[g];
    float bias = bih[g] + bhh[g];
    REP9(PINQ, R)
    asm volatile("" : "+v"(wx), "+v"(bias));

    if (g < 40) hs[cc][g] = 0.0f;
    float c = 0.0f;
    __syncthreads();

    float* dst = h0r + (size_t)b * TT * Hn;

    for (int s = 0; s < TT; ++s) {
        const int t = TT - 1 - s;
        float z0 = fmaf(xs[cc][t], wx, bias), z1 = 0.f, z2 = 0.f, z3 = 0.f;
        {
            const float* hb = hs[cc];
            REP9(FMAQ, R)
        }
        zs[cc][g] = (z0 + z1) + (z2 + z3);
        __syncthreads();
        if (g < Hn) {
            float zi = zs[cc][g], zf = zs[cc][g + 36], zg = zs[cc][g + 72], zo = zs[cc][g + 108];
            c = sigf(zf) * c + sigf(zi) * tanh_fast(zg);
            float h = sigf(zo) * tanh_fast(c);
            hs[cc][g] = h;
            dst[(size_t)t * Hn + g] = h;
        }
        __syncthreads();
    }
}

// ===== K2: skewed fusion of L0-forward + L1-forward + 1-step L1-rev + FC =====
// 4 groups x 144 rows, one chain per block. Group F produces h0f(t+1) while
// the three L groups consume h0cat(t) and h1(t-1). h0r streamed + prefetched.
#define NT2 576
__global__ __launch_bounds__(NT2) void fused_fl_kernel(
    const float* __restrict__ x,
    const float* __restrict__ Wih0f, const float* __restrict__ Whh0f,
    const float* __restrict__ bih0f, const float* __restrict__ bhh0f,
    const float* __restrict__ Wih1f, const float* __restrict__ Whh1f,
    const float* __restrict__ bih1f, const float* __restrict__ bhh1f,
    const float* __restrict__ Wih1r,
    const float* __restrict__ bih1r, const float* __restrict__ bhh1r,
    const float* __restrict__ fcW, const float* __restrict__ fcb,
    const float* __restrict__ h0r,
    float* __restrict__ out)
{
    const int tid = threadIdx.x;
    const int gp  = tid / G4;    // 0:F  1:L-ih(h0f)  2:L-ih(h0r)  3:L-hh(h1)
    const int g   = tid % G4;
    const int b   = blockIdx.x;

    __shared__ float xs[TT + 2];
    __shared__ float h0f[2][40];    // double-buffered L0f state
    __shared__ float h0rs[2][40];   // double-buffered h0r(t) window
    __shared__ float h1[40];
    __shared__ float zF[G4];
    __shared__ float zL[3][G4];
    __shared__ float red[40];

    for (int i = tid; i < TT; i += NT2) xs[i] = x[(size_t)b * TT + i];
    if (tid == 0) { xs[TT] = 0.0f; xs[TT + 1] = 0.0f; }

    const float* wp0 = (gp == 0) ? (Whh0f + g * Hn)
                     : (gp == 1) ? (Wih1f + g * 72)
                     : (gp == 2) ? (Wih1f + g * 72 + 36)
                                 : (Whh1f + g * Hn);
    REP9(DECLQ, W)
    {
        const float4* wp = (const float4*)wp0;
        REP9(LOADQ, W)
    }
    float wx0  = (gp == 0) ? Wih0f[g] : 0.0f;
    float bsum = (gp == 0) ? (bih0f[g] + bhh0f[g])
               : (gp == 3) ? (bih1f[g] + bhh1f[g]) : 0.0f;
    REP9(PINQ, W)
    asm volatile("" : "+v"(wx0), "+v"(bsum));

    const float* srow = h0r + (size_t)b * TT * Hn;

    if (gp == 2 && g < Hn) h0rs[0][g] = srow[g];        // h0r(0)
    if (gp == 3 && g < 40) h1[g] = 0.0f;
    if (tid < 4) {                                      // zero pads of all bufs
        h0f[0][36 + tid] = 0.0f; h0f[1][36 + tid] = 0.0f;
        h0rs[0][36 + tid] = 0.0f; h0rs[1][36 + tid] = 0.0f;
    }
    float c0 = 0.0f, c1 = 0.0f;
    __syncthreads();

    // ---- prologue: h0f(0) = step(h=0, x0)  (z = wx0*x0 + b0) ----
    if (gp == 0) zF[g] = fmaf(xs[0], wx0, bsum);
    __syncthreads();
    if (gp == 0 && g < Hn) {
        float zi = zF[g], zf = zF[g + 36], zg = zF[g + 72], zo = zF[g + 108];
        c0 = sigf(zf) * c0 + sigf(zi) * tanh_fast(zg);
        h0f[0][g] = sigf(zo) * tanh_fast(c0);
    }
    __syncthreads();

    int cur = 0;
    float rvN = (gp == 2 && g < Hn) ? srow[Hn + g] : 0.0f;   // h0r(1)

    for (int t = 0; t < TT; ++t) {
        float rv2 = (gp == 2 && g < Hn && t + 2 < TT)
                  ? srow[(size_t)(t + 2) * Hn + g] : 0.0f;

        const float* hb = (gp == 0 || gp == 1) ? h0f[cur]
                        : (gp == 2) ? h0rs[cur] : h1;
        float z0 = (gp == 0) ? fmaf(xs[t + 1], wx0, bsum)
                 : (gp == 3) ? bsum : 0.0f;
        float z1 = 0.f, z2 = 0.f, z3 = 0.f;
        REP9(FMAQ, W)
        float zv = (z0 + z1) + (z2 + z3);
        if (gp == 0) zF[g] = zv; else zL[gp - 1][g] = zv;
        __syncthreads();

        if (gp == 0) {
            if (g < Hn && t + 1 < TT) {        // produce h0f(t+1)
                float zi = zF[g], zf = zF[g + 36], zg = zF[g + 72], zo = zF[g + 108];
                c0 = sigf(zf) * c0 + sigf(zi) * tanh_fast(zg);
                h0f[cur ^ 1][g] = sigf(zo) * tanh_fast(c0);
            }
        } else if (gp == 3) {
            if (g < Hn) {                      // produce h1(t)
                float zi = zL[0][g]       + zL[1][g]       + zL[2][g];
                float zf = zL[0][g + 36]  + zL[1][g + 36]  + zL[2][g + 36];
                float zg = zL[0][g + 72]  + zL[1][g + 72]  + zL[2][g + 72];
                float zo = zL[0][g + 108] + zL[1][g + 108] + zL[2][g + 108];
                c1 = sigf(zf) * c1 + sigf(zi) * tanh_fast(zg);
                h1[g] = sigf(zo) * tanh_fast(c1);
            }
        } else if (gp == 2 && g < Hn && t + 1 < TT) {
            h0rs[cur ^ 1][g] = rvN;            // stage h0r(t+1)
        }
        __syncthreads();
        rvN = rv2;
        if (t + 1 < TT) cur ^= 1;
    }

    // ---- tail: L1 reverse single step at t=T-1 (h0=c0=0) + FC ----
    if (gp == 0) {
        float zR = bih1r[g] + bhh1r[g];
        const float* wr = Wih1r + g * 72;
#pragma unroll
        for (int k = 0; k < Hn; ++k) zR = fmaf(wr[k], h0f[cur][k], zR);
        zF[g] = zR;
    } else if (gp == 2) {
        float zR = 0.0f;
        const float* wr = Wih1r + g * 72 + 36;
#pragma unroll
        for (int k = 0; k < Hn; ++k) zR = fmaf(wr[k], h0rs[cur][k], zR);
        zL[0][g] = zR;
    }
    __syncthreads();
    if (tid < Hn) {
        float zi = zF[tid]       + zL[0][tid];
        float zg = zF[tid + 72]  + zL[0][tid + 72];
        float zo = zF[tid + 108] + zL[0][tid + 108];
        float c  = sigf(zi) * tanh_fast(zg);     // c0=0: forget term vanishes
        float hR = sigf(zo) * tanh_fast(c);
        red[tid] = fcW[36 + tid] * hR + fcW[tid] * h1[tid];
    }
    __syncthreads();
    if (tid == 0) {
        float s2 = fcb[0];
        for (int j = 0; j < Hn; ++j) s2 += red[j];
        out[b] = s2;
    }
}

// ================= FALLBACK PATH (zero workspace, ckpt/recompute) ============
__global__ __launch_bounds__(G4, 1) void fused_all_kernel(
    const float* __restrict__ x,
    const float* __restrict__ Wih0f, const float* __restrict__ Whh0f,
    const float* __restrict__ bih0f, const float* __restrict__ bhh0f,
    const float* __restrict__ Wih0r, const float* __restrict__ Whh0r,
    const float* __restrict__ bih0r, const float* __restrict__ bhh0r,
    const float* __restrict__ Wih1f, const float* __restrict__ Whh1f,
    const float* __restrict__ bih1f, const float* __restrict__ bhh1f,
    const float* __restrict__ Wih1r,
    const float* __restrict__ bih1r, const float* __restrict__ bhh1r,
    const float* __restrict__ fcW, const float* __restrict__ fcb,
    float* __restrict__ out)
{
    const int g = threadIdx.x;
    const int b = blockIdx.x;

    __shared__ float xs[TT];
    __shared__ float cbuf[64][Hn];
    __shared__ float ckpt_h[8][Hn], ckpt_c[8][Hn];
    __shared__ float hr[40], h0s[80], hs1[40], zs[G4], red[40];

    for (int i = g; i < TT; i += G4) xs[i] = x[(size_t)b * TT + i];

    float wr[Hn], wf[Hn];
#pragma unroll
    for (int k = 0; k < Hn; ++k) wr[k] = Whh0r[g * Hn + k];
#pragma unroll
    for (int k = 0; k < Hn; ++k) wf[k] = Whh0f[g * Hn + k];
    const float wxr = Wih0r[g], br = bih0r[g] + bhh0r[g];
    const float wxf = Wih0f[g], bf = bih0f[g] + bhh0f[g];
    float w1i[72];
#pragma unroll
    for (int k = 0; k < 72; ++k) w1i[k] = Wih1f[g * 72 + k];
    float w1h[Hn];
#pragma unroll
    for (int k = 0; k < Hn; ++k) w1h[k] = Whh1f[g * Hn + k];
    const float b1 = bih1f[g] + bhh1f[g];

    if (g < Hn) hr[g] = 0.0f;
    float cr = 0.0f;
    __syncthreads();
    for (int s = 0; s < TT; ++s) {
        const int t = TT - 1 - s;
        if ((t & 63) == 63 && g < Hn) { ckpt_h[t >> 6][g] = hr[g]; ckpt_c[t >> 6][g] = cr; }
        float z0 = fmaf(xs[t], wxr, br), z1 = 0.f, z2 = 0.f, z3 = 0.f;
        DOT36(wr, hr, z0, z1, z2, z3);
        zs[g] = (z0 + z1) + (z2 + z3);
        __syncthreads();
        if (g < Hn) {
            float zi = zs[g], zf = zs[g + 36], zg = zs[g + 72], zo = zs[g + 108];
            cr = sigf(zf) * cr + sigf(zi) * tanh_fast(zg);
            hr[g] = sigf(zo) * tanh_fast(cr);
        }
        __syncthreads();
    }

    if (g < Hn) { h0s[g] = 0.0f; hs1[g] = 0.0f; }
    float c0 = 0.0f, c1 = 0.0f;
    __syncthreads();

    for (int m = 0; m < 8; ++m) {
        if (g < Hn) { hr[g] = ckpt_h[m][g]; cr = ckpt_c[m][g]; }
        __syncthreads();
        for (int j = 0; j < 64; ++j) {
            const int t = m * 64 + 63 - j;
            float z0 = fmaf(xs[t], wxr, br), z1 = 0.f, z2 = 0.f, z3 = 0.f;
            DOT36(wr, hr, z0, z1, z2, z3);
            zs[g] = (z0 + z1) + (z2 + z3);
            __syncthreads();
            if (g < Hn) {
                float zi = zs[g], zf = zs[g + 36], zg = zs[g + 72], zo = zs[g + 108];
                cr = sigf(zf) * cr + sigf(zi) * tanh_fast(zg);
                float h = sigf(zo) * tanh_fast(cr);
                hr[g] = h;
                cbuf[t & 63][g] = h;
            }
            __syncthreads();
        }
        for (int j = 0; j < 64; ++j) {
            const int t = m * 64 + j;
            float z0 = fmaf(xs[t], wxf, bf), z1 = 0.f, z2 = 0.f, z3 = 0.f;
            DOT36(wf, h0s, z0, z1, z2, z3);
            zs[g] = (z0 + z1) + (z2 + z3);
            __syncthreads();
            if (g < Hn) {
                float zi = zs[g], zf = zs[g + 36], zg = zs[g + 72], zo = zs[g + 108];
                c0 = sigf(zf) * c0 + sigf(zi) * tanh_fast(zg);
                h0s[g] = sigf(zo) * tanh_fast(c0);
            } else if (g < 72) {
                h0s[g] = cbuf[j][g - 36];
            }
            __syncthreads();
            float y0 = b1, y1 = 0.f, y2 = 0.f, y3 = 0.f;
            DOT72(w1i, h0s, y0, y1, y2, y3);
            DOT36(w1h, hs1, y0, y1, y2, y3);
            zs[g] = (y0 + y1) + (y2 + y3);
            __syncthreads();
            if (g < Hn) {
                float zi = zs[g], zf = zs[g + 36], zg = zs[g + 72], zo = zs[g + 108];
                c1 = sigf(zf) * c1 + sigf(zi) * tanh_fast(zg);
                hs1[g] = sigf(zo) * tanh_fast(c1);
            }
            __syncthreads();
        }
    }

    float zR = bih1r[g] + bhh1r[g];
#pragma unroll
    for (int k = 0; k < 72; ++k) zR = fmaf(Wih1r[g * 72 + k], h0s[k], zR);
    zs[g] = zR;
    __syncthreads();
    if (g < Hn) {
        float zi = zs[g], zg = zs[g + 72], zo = zs[g + 108];
        float c  = sigf(zi) * tanh_fast(zg);
        float hrv = sigf(zo) * tanh_fast(c);
        red[g] = fcW[36 + g] * hrv + fcW[g] * hs1[g];
    }
    __syncthreads();
    if (g == 0) {
        float s = fcb[0];
        for (int j = 0; j < Hn; ++j) s += red[j];
        out[b] = s;
    }
}

extern "C" void kernel_launch(void* const* d_in, const int* in_sizes, int n_in,
                              void* d_out, int out_size, void* d_ws, size_t ws_size,
                              hipStream_t stream)
{
    const float* x     = (const float*)d_in[0];
    const float* Wih0f = (const float*)d_in[1];
    const float* Whh0f = (const float*)d_in[2];
    const float* bih0f = (const float*)d_in[3];
    const float* bhh0f = (const float*)d_in[4];
    const float* Wih0r = (const float*)d_in[5];
    const float* Whh0r = (const float*)d_in[6];
    const float* bih0r = (const float*)d_in[7];
    const float* bhh0r = (const float*)d_in[8];
    const float* Wih1f = (const float*)d_in[9];
    const float* Whh1f = (const float*)d_in[10];
    const float* bih1f = (const float*)d_in[11];
    const float* bhh1f = (const float*)d_in[12];
    const float* Wih1r = (const float*)d_in[13];
    const float* bih1r = (const float*)d_in[15];
    const float* bhh1r = (const float*)d_in[16];
    const float* fcW   = (const float*)d_in[17];
    const float* fcb   = (const float*)d_in[18];

    const size_t need = (size_t)BB * TT * Hn * sizeof(float);   // 151 MB (known-safe)
    if (d_ws != nullptr && ws_size >= need) {
        float* h0r = (float*)d_ws;
        l0rev_kernel<<<BB / SG1, NTK1, 0, stream>>>(x, Wih0r, Whh0r, bih0r, bhh0r, h0r);
        fused_fl_kernel<<<BB, NT2, 0, stream>>>(
            x, Wih0f, Whh0f, bih0f, bhh0f, Wih1f, Whh1f, bih1f, bhh1f,
            Wih1r, bih1r, bhh1r, fcW, fcb, h0r, (float*)d_out);
    } else {
        fused_all_kernel<<<BB, G4, 0, stream>>>(
            x, Wih0f, Whh0f, bih0f, bhh0f, Wih0r, Whh0r, bih0r, bhh0r,
            Wih1f, Whh1f, bih1f, bhh1f, Wih1r, bih1r, bhh1r, fcW, fcb,
            (float*)d_out);
    }
}